// Round 2
// baseline (231.642 us; speedup 1.0000x reference)
//
#include <hip/hip_runtime.h>
#include <hip/hip_bf16.h>
#include <cstdint>

typedef __bf16 bf16x4 __attribute__((ext_vector_type(4)));
typedef float  f32x4  __attribute__((ext_vector_type(4)));
typedef int    i32x4  __attribute__((ext_vector_type(4)));
typedef int    i32x8  __attribute__((ext_vector_type(8)));

#define B_ROWS 4096
#define IN_DIM 1024
#define HIDDEN 8192
#define KEEP   256

using gptr_t = const __attribute__((address_space(1))) void*;
using lptr_t = __attribute__((address_space(3))) void*;

__device__ __forceinline__ void async_load16(const void* g, void* l) {
    gptr_t gp = reinterpret_cast<gptr_t>(reinterpret_cast<uintptr_t>(g));
    lptr_t lp = reinterpret_cast<lptr_t>(reinterpret_cast<uintptr_t>(l));
    __builtin_amdgcn_global_load_lds(gp, lp, 16, 0, 0);
}

__device__ __forceinline__ unsigned char f32_to_fp8(float v) {
    return (unsigned char)(__builtin_amdgcn_cvt_pk_fp8_f32(v, v, 0, false) & 0xFF);
}

template<int N> __device__ __forceinline__ void vmwait() {
    if constexpr      (N == 0) asm volatile("s_waitcnt vmcnt(0)" ::: "memory");
    else if constexpr (N == 2) asm volatile("s_waitcnt vmcnt(2)" ::: "memory");
    else if constexpr (N == 3) asm volatile("s_waitcnt vmcnt(3)" ::: "memory");
    else                       asm volatile("s_waitcnt vmcnt(4)" ::: "memory");
}

// ---------------------------------------------------------------------------
// C[M,N] = A[M,K] @ B[N,K]^T, fp8 e4m3, MX MFMA (unit scales), fp32 accum.
// EPI==0: fp8 C (encode).  EPI==1: bf16 C partial z (decode).
//
// R10: m201-style 4-phase schedule on a 2-buf (per-K-tile) LDS dbuf.
//  - BM=256; encode BN=256 (per-wave 128x64, 85 FLOP/LDS-byte -> MFMA-
//    balanced), decode BN=128 (per-wave 64x64).
//  - Each K-step = 4 phases; phase = one C-quadrant x full K=128B:
//    {ds_read quadrant frags; stage 1 half-tile (gload_lds); s_barrier;
//     setprio(1) 8|4 MFMA setprio(0); counted vmcnt; s_barrier}.
//  - Half-tiles are WAVE-STRIPE sets matched to quadrant read-sets:
//    A-h / B-h = union of each wave's m-/n-half rows. Stage order per group
//    [A-h0 | B-h0 | B-h1 | A-h1]; per-phase vmcnt N = calls(this)+calls(prev)
//    (encode 4,4,4,4; decode 4,3,2,3; tail 2,0,0,0) => every read-set is
//    vmcnt+barrier-guaranteed, loads never drain to 0 mid-loop.
//  - Race-freedom: group k reads buf[k&1], stages buf[(k+1)&1] whose last
//    readers (group k-1) passed >=1 barrier earlier.
// HISTORY: r6 single-buf 128^2: 51.7us/GEMM, MfmaUtil 25%. r9 3-buf ring
// 256x128: 54.5us, MfmaUtil 24% -> counted vmcnt alone is null without the
// phase interleave (catalog regime gate); LDS-read serialization binds.
// ---------------------------------------------------------------------------
template<int BN, int WR, int WC, int EPI>
__global__ __launch_bounds__(512, 2)
void gemm_p4(const unsigned char* __restrict__ A, int lda,
             const unsigned char* __restrict__ Bm, int ldb,
             void* __restrict__ Cout, int M, int N, int Kloop)
{
    constexpr int BM  = 256, BKB = 128;
    constexpr int WTM = BM / WR / 16;      // encode 8, decode 4
    constexpr int WTN = BN / WC / 16;      // 4 in both configs
    constexpr int HM  = WTM / 2, HN = WTN / 2;
    constexpr int ASW = WTM * 8;           // A half-stripe width: 64 or 32
    constexpr int BC  = (BN / 2) / 64;     // B gload calls per half: 2 or 1
    constexpr int SZ  = (BM + BN) * BKB;   // bytes per K-tile buffer
    constexpr int BOFF = BM * BKB;

    __shared__ __align__(16) unsigned char smem[2 * SZ];

    const int tid  = threadIdx.x;
    const int wave = tid >> 6;
    const int lane = tid & 63;

    // XCD-aware bijective swizzle (nwg % 8 == 0: encode 512, decode 128/plane)
    const int gx  = gridDim.x;
    const int nwg = gx * gridDim.y;
    const int lin = blockIdx.y * gx + blockIdx.x;
    const int q   = nwg >> 3;
    const int swz = (lin & 7) * q + (lin >> 3);
    const int bx = swz % gx, by = swz / gx;

    const long long block_m = (long long)by * BM;
    const long long block_n = (long long)bx * BN;

    A  += (long long)blockIdx.z * Kloop;
    Bm += (long long)blockIdx.z * Kloop;

    const int wm = (wave / WC) * (WTM * 16);
    const int wn = (wave % WC) * (WTN * 16);

    const int sub_row = lane >> 3;
    const int slot    = lane & 7;
    const int kg_sw   = (slot ^ sub_row) * 16; // global-side XOR pre-swizzle
    const int koff    = slot * 16;             // linear LDS dest

    const int lm = lane & 15;
    const int lq = lane >> 4;

    f32x4 acc[WTM][WTN] = {};
    i32x8 afr[HM], bfr[WTN];

    const int NK = Kloop / BKB;

    // ---- staging: one half-tile (A or B, half hh) = stripes matched to
    //      the quadrant read-sets; per-wave dest contiguous (gload_lds rule).
    auto stageA = [&](int hh, unsigned char* wb, long long kt) {
        #pragma unroll
        for (int c = 0; c < 2; ++c) {
            int row;
            if constexpr (ASW == 64) row = c * 128 + hh * 64 + wave * 8 + sub_row;
            else row = (2 * c + (wave >> 2)) * 64 + hh * 32 + (wave & 3) * 8 + sub_row;
            async_load16(A + (block_m + row) * (long long)lda + kt + kg_sw,
                         wb + row * BKB + koff);
        }
    };
    auto stageB = [&](int hh, unsigned char* wb, long long kt) {
        #pragma unroll
        for (int c = 0; c < BC; ++c) {
            const int row = (2 * c + (wave >> 2)) * 64 + hh * 32 + (wave & 3) * 8 + sub_row;
            async_load16(Bm + (block_n + row) * (long long)ldb + kt + kg_sw,
                         wb + BOFF + row * BKB + koff);
        }
    };
    auto rdA = [&](const unsigned char* rb, int i, i32x8& d) {
        const int r = wm + i * 16 + lm;
        const i32x4 lo = *(const i32x4*)(rb + r * BKB + (((2 * lq)     ^ (r & 7)) * 16));
        const i32x4 hi = *(const i32x4*)(rb + r * BKB + (((2 * lq + 1) ^ (r & 7)) * 16));
        d = i32x8{lo.x, lo.y, lo.z, lo.w, hi.x, hi.y, hi.z, hi.w};
    };
    auto rdB = [&](const unsigned char* rb, int j, i32x8& d) {
        const int r = wn + j * 16 + lm;
        const i32x4 lo = *(const i32x4*)(rb + BOFF + r * BKB + (((2 * lq)     ^ (r & 7)) * 16));
        const i32x4 hi = *(const i32x4*)(rb + BOFF + r * BKB + (((2 * lq + 1) ^ (r & 7)) * 16));
        d = i32x8{lo.x, lo.y, lo.z, lo.w, hi.x, hi.y, hi.z, hi.w};
    };

    // ---- prologue: stage tile 0 halves in order [A-h0, B-h0, B-h1, A-h1];
    //      drain through B-h0 (leave last BC+2 calls = B-h1,A-h1 in flight).
    stageA(0, smem, 0);
    stageB(0, smem, 0);
    stageB(1, smem, 0);
    stageA(1, smem, 0);
    vmwait<BC + 2>();
    __builtin_amdgcn_s_barrier();

    for (int k = 0; k < NK; ++k) {
        const unsigned char* rb = smem + (size_t)(k & 1) * SZ;
        unsigned char*       wb = smem + (size_t)((k + 1) & 1) * SZ;
        const bool st = (k + 1 < NK);
        const long long kt = (long long)(k + 1) * BKB;

        // ---------- P1: quadrant (m-lo, n-lo); stage A-h0(k+1)
        #pragma unroll
        for (int i = 0; i < HM; ++i) rdA(rb, i, afr[i]);
        #pragma unroll
        for (int j = 0; j < HN; ++j) rdB(rb, j, bfr[j]);
        if (st) stageA(0, wb, kt);
        __builtin_amdgcn_s_barrier();
        __builtin_amdgcn_s_setprio(1);
        #pragma unroll
        for (int i = 0; i < HM; ++i)
            #pragma unroll
            for (int j = 0; j < HN; ++j)
                acc[i][j] = __builtin_amdgcn_mfma_scale_f32_16x16x128_f8f6f4(
                    afr[i], bfr[j], acc[i][j], 0, 0, 0, 0x7F7F7F7F, 0, 0x7F7F7F7F);
        __builtin_amdgcn_s_setprio(0);
        if (st) vmwait<4>(); else vmwait<2>();
        __builtin_amdgcn_s_barrier();

        // ---------- P2: quadrant (m-lo, n-hi); stage B-h0(k+1)
        #pragma unroll
        for (int j = 0; j < HN; ++j) rdB(rb, HN + j, bfr[HN + j]);
        if (st) stageB(0, wb, kt);
        __builtin_amdgcn_s_barrier();
        __builtin_amdgcn_s_setprio(1);
        #pragma unroll
        for (int i = 0; i < HM; ++i)
            #pragma unroll
            for (int j = 0; j < HN; ++j)
                acc[i][HN + j] = __builtin_amdgcn_mfma_scale_f32_16x16x128_f8f6f4(
                    afr[i], bfr[HN + j], acc[i][HN + j], 0, 0, 0, 0x7F7F7F7F, 0, 0x7F7F7F7F);
        __builtin_amdgcn_s_setprio(0);
        if (st) vmwait<BC + 2>(); else vmwait<0>();
        __builtin_amdgcn_s_barrier();

        // ---------- P3: quadrant (m-hi, n-hi); stage B-h1(k+1)
        #pragma unroll
        for (int i = 0; i < HM; ++i) rdA(rb, HM + i, afr[i]);   // overwrite af
        if (st) stageB(1, wb, kt);
        __builtin_amdgcn_s_barrier();
        __builtin_amdgcn_s_setprio(1);
        #pragma unroll
        for (int i = 0; i < HM; ++i)
            #pragma unroll
            for (int j = 0; j < HN; ++j)
                acc[HM + i][HN + j] = __builtin_amdgcn_mfma_scale_f32_16x16x128_f8f6f4(
                    afr[i], bfr[HN + j], acc[HM + i][HN + j], 0, 0, 0, 0x7F7F7F7F, 0, 0x7F7F7F7F);
        __builtin_amdgcn_s_setprio(0);
        if (st) vmwait<2 * BC>(); else vmwait<0>();
        __builtin_amdgcn_s_barrier();

        // ---------- P4: quadrant (m-hi, n-lo); stage A-h1(k+1)
        if (st) stageA(1, wb, kt);
        __builtin_amdgcn_s_barrier();
        __builtin_amdgcn_s_setprio(1);
        #pragma unroll
        for (int i = 0; i < HM; ++i)
            #pragma unroll
            for (int j = 0; j < HN; ++j)
                acc[HM + i][j] = __builtin_amdgcn_mfma_scale_f32_16x16x128_f8f6f4(
                    afr[i], bfr[j], acc[HM + i][j], 0, 0, 0, 0x7F7F7F7F, 0, 0x7F7F7F7F);
        __builtin_amdgcn_s_setprio(0);
        if (st) vmwait<BC + 2>(); else vmwait<0>();
        __builtin_amdgcn_s_barrier();
    }

    // D[m][n]: n = lane&15, m = 4*(lane>>4)+r
    const int rbase = lq * 4;
    if constexpr (EPI == 0) {
        unsigned char* Hh = (unsigned char*)Cout;
        #pragma unroll
        for (int i = 0; i < WTM; ++i)
            #pragma unroll
            for (int j = 0; j < WTN; ++j)
                #pragma unroll
                for (int r = 0; r < 4; ++r) {
                    const long long m = block_m + wm + i * 16 + rbase + r;
                    const long long n = block_n + wn + j * 16 + lm;
                    Hh[m * N + n] = f32_to_fp8(acc[i][j][r]);
                }
    } else {
        __bf16* Cp = (__bf16*)Cout + (size_t)blockIdx.z * (size_t)M * N;
        #pragma unroll
        for (int i = 0; i < WTM; ++i)
            #pragma unroll
            for (int j = 0; j < WTN; ++j)
                #pragma unroll
                for (int r = 0; r < 4; ++r) {
                    const long long m = block_m + wm + i * 16 + rbase + r;
                    const long long n = block_n + wn + j * 16 + lm;
                    Cp[m * N + n] = (__bf16)acc[i][j][r];
                }
    }
}

// ---------------------------------------------------------------------------
// out = x + gate * (P0 + P1)   (bf16 partials -> fp32 out)
// ---------------------------------------------------------------------------
__global__ __launch_bounds__(256)
void reduce_out(const __bf16* __restrict__ P, const float* __restrict__ x,
                const float* __restrict__ gate, float* __restrict__ out)
{
    const int i = blockIdx.x * 256 + threadIdx.x;
    const float4 xv = ((const float4*)x)[i];
    const bf16x4 p0 = ((const bf16x4*)P)[i];
    const bf16x4 p1 = ((const bf16x4*)(P + (size_t)B_ROWS * IN_DIM))[i];
    const float4 g  = ((const float4*)gate)[i & (IN_DIM / 4 - 1)];
    float4 o;
    o.x = xv.x + g.x * ((float)p0.x + (float)p1.x);
    o.y = xv.y + g.y * ((float)p0.y + (float)p1.y);
    o.z = xv.z + g.z * ((float)p0.z + (float)p1.z);
    o.w = xv.w + g.w * ((float)p0.w + (float)p1.w);
    ((float4*)out)[i] = o;
}

// ---------------------------------------------------------------------------
// One dispatch: cast Wenc+Wdec fp32->fp8 (blocks 0..16383) and
// row-normalize x -> fp8 (blocks 16384..20479).
// ---------------------------------------------------------------------------
__global__ __launch_bounds__(256)
void prep(const float* __restrict__ Wenc, const float* __restrict__ Wdec,
          const float* __restrict__ x,
          unsigned char* __restrict__ WencB, unsigned char* __restrict__ WdecB,
          unsigned char* __restrict__ xn)
{
    constexpr int N4 = HIDDEN * IN_DIM / 4;
    constexpr int WBLK = 2 * N4 / 256;
    const int t = threadIdx.x;

    if (blockIdx.x < WBLK) {
        int i = blockIdx.x * 256 + t;
        const float* src; unsigned char* dst;
        if (i < N4) { src = Wenc; dst = WencB; }
        else        { src = Wdec; dst = WdecB; i -= N4; }
        const float4 v = ((const float4*)src)[i];
        int p = __builtin_amdgcn_cvt_pk_fp8_f32(v.x, v.y, 0, false);
        p     = __builtin_amdgcn_cvt_pk_fp8_f32(v.z, v.w, p, true);
        ((int*)dst)[i] = p;
    } else {
        const int row = blockIdx.x - WBLK;
        const float4 v = ((const float4*)(x + (long long)row * IN_DIM))[t];
        float ss = v.x * v.x + v.y * v.y + v.z * v.z + v.w * v.w;
        #pragma unroll
        for (int off = 32; off > 0; off >>= 1) ss += __shfl_down(ss, off);
        __shared__ float part[4];
        if ((t & 63) == 0) part[t >> 6] = ss;
        __syncthreads();
        const float tot = part[0] + part[1] + part[2] + part[3];
        const float inv = 1.0f / fmaxf(sqrtf(tot), 1e-12f);
        int p = __builtin_amdgcn_cvt_pk_fp8_f32(v.x * inv, v.y * inv, 0, false);
        p     = __builtin_amdgcn_cvt_pk_fp8_f32(v.z * inv, v.w * inv, p, true);
        ((int*)(xn + (long long)row * IN_DIM))[t] = p;
    }
}

// ---------------------------------------------------------------------------
// Per-row top-K mask in place on fp8 hidden.
// ---------------------------------------------------------------------------
__global__ __launch_bounds__(256)
void topk_mask8(unsigned int* __restrict__ H)
{
    __shared__ unsigned int hist8[256 * 8];
    __shared__ unsigned int sT;
    const int t = threadIdx.x;
    unsigned int* row = H + (size_t)blockIdx.x * (HIDDEN / 4);

    #pragma unroll
    for (int i = 0; i < 8; ++i) hist8[i * 256 + t] = 0;
    __syncthreads();

    unsigned int rw[8];
    const int cp = t & 7;
    #pragma unroll
    for (int i = 0; i < 8; ++i) {
        rw[i] = row[i * 256 + t];
        #pragma unroll
        for (int e = 0; e < 4; ++e) {
            const unsigned int b = (rw[i] >> (8 * e)) & 0xFFu;
            const unsigned int k = b ^ ((b & 0x80u) ? 0xFFu : 0x80u);
            atomicAdd(&hist8[k * 8 + cp], 1u);
        }
    }
    __syncthreads();

    unsigned int cnt = 0;
    #pragma unroll
    for (int c = 0; c < 8; ++c) cnt += hist8[t * 8 + c];
    __syncthreads();
    hist8[t] = cnt;
    __syncthreads();

    if (t < 64) {
        const uint4 c4 = *(const uint4*)&hist8[4 * t];
        const unsigned s3 = c4.w;
        const unsigned s2 = c4.z + s3;
        const unsigned s1 = c4.y + s2;
        const unsigned s0 = c4.x + s1;
        unsigned inc = s0;
        #pragma unroll
        for (int off = 1; off < 64; off <<= 1) {
            unsigned o = __shfl_down(inc, off);
            if (t + off >= 64) o = 0;
            inc += o;
        }
        const unsigned carry = inc - s0;
        const unsigned a0 = s0 + carry, a1 = s1 + carry;
        const unsigned a2 = s2 + carry, a3 = s3 + carry;
        if (a0 >= KEEP && a1 < KEEP)    sT = 4u * t + 0u;
        if (a1 >= KEEP && a2 < KEEP)    sT = 4u * t + 1u;
        if (a2 >= KEEP && a3 < KEEP)    sT = 4u * t + 2u;
        if (a3 >= KEEP && carry < KEEP) sT = 4u * t + 3u;
    }
    __syncthreads();
    const unsigned int T = sT;

    #pragma unroll
    for (int i = 0; i < 8; ++i) {
        const unsigned int kw = rw[i];
        unsigned int ow = 0;
        #pragma unroll
        for (int e = 0; e < 4; ++e) {
            const unsigned int b = (kw >> (8 * e)) & 0xFFu;
            const unsigned int k = b ^ ((b & 0x80u) ? 0xFFu : 0x80u);
            if (k >= T) ow |= b << (8 * e);
        }
        row[i * 256 + t] = ow;
    }
}

// ---------------------------------------------------------------------------
extern "C" void kernel_launch(void* const* d_in, const int* in_sizes, int n_in,
                              void* d_out, int out_size, void* d_ws, size_t ws_size,
                              hipStream_t stream)
{
    const float* x    = (const float*)d_in[0];   // [4096,1024]
    const float* Wenc = (const float*)d_in[1];   // [8192,1024]
    const float* Wdec = (const float*)d_in[2];   // [1024,8192]
    const float* gate = (const float*)d_in[3];   // [1024]
    float* out = (float*)d_out;

    char* ws = (char*)d_ws;
    unsigned char* xn    = (unsigned char*)(ws);                        //  4 MB
    unsigned char* WencB = (unsigned char*)(ws + (size_t)( 4 << 20));   //  8 MB
    unsigned char* WdecB = (unsigned char*)(ws + (size_t)(12 << 20));   //  8 MB
    unsigned char* Hbuf  = (unsigned char*)(ws + (size_t)(20 << 20));   // 32 MB
    __bf16*        Part  = (__bf16*)       (ws + (size_t)(52 << 20));   // 16 MB

    constexpr int N4 = HIDDEN * IN_DIM / 4;
    prep<<<2 * N4 / 256 + B_ROWS, 256, 0, stream>>>(Wenc, Wdec, x, WencB, WdecB, xn);

    // hidden[4096,8192] = xn @ Wenc^T  (fp8 out): 256x256 tile, waves 2x4
    gemm_p4<256, 2, 4, 0><<<dim3(HIDDEN / 256, B_ROWS / 256, 1), 512, 0, stream>>>(
        xn, IN_DIM, WencB, IN_DIM, (void*)Hbuf, B_ROWS, HIDDEN, IN_DIM);

    topk_mask8<<<B_ROWS, 256, 0, stream>>>((unsigned int*)Hbuf);

    // partials[z][4096,1024] = act_z @ Wdec_z^T  (bf16, split-K=2):
    // 256x128 tile, waves 4x2
    gemm_p4<128, 4, 2, 1><<<dim3(IN_DIM / 128, B_ROWS / 256, 2), 512, 0, stream>>>(
        Hbuf, HIDDEN, WdecB, HIDDEN, (void*)Part, B_ROWS, IN_DIM, HIDDEN / 2);

    reduce_out<<<B_ROWS * IN_DIM / 4 / 256, 256, 0, stream>>>(Part, x, gate, out);
}